// Round 20
// baseline (467.504 us; speedup 1.0000x reference)
//
#include <hip/hip_runtime.h>
#include <stdint.h>

#define Bn 2
#define Sn 2048
#define Dn 3584
#define Hn 28
#define KVn 4
#define HDn 128

typedef __bf16 bf16x8 __attribute__((ext_vector_type(8)));
typedef float f32x4 __attribute__((ext_vector_type(4)));

__device__ __forceinline__ unsigned short f2bf(float f){
  union { float f; unsigned u; } a; a.f = f;
  unsigned r = a.u + 0x7fffu + ((a.u >> 16) & 1u);
  return (unsigned short)(r >> 16);
}
__device__ __forceinline__ float bf2f(unsigned short s){
  union { unsigned u; float f; } a; a.u = ((unsigned)s) << 16; return a.f;
}

// DPP row-rotate (16-lane row), full-rate VALU cross-lane.
template<int CTRL>
__device__ __forceinline__ float dppf(float x){
  return __int_as_float(__builtin_amdgcn_update_dpp(0, __float_as_int(x), CTRL, 0xf, 0xf, true));
}

// global -> LDS direct copy, 16B per lane. lds must be wave-uniform; HW adds lane*16.
__device__ __forceinline__ void glds16(const unsigned short* g, const unsigned short* lds){
  __builtin_amdgcn_global_load_lds(
      (const __attribute__((address_space(1))) void*)(uintptr_t)g,
      (__attribute__((address_space(3))) void*)(uintptr_t)lds,
      16, 0, 0);
}

// Fused 4-segment fp32->bf16 cast (one launch for X, Wq, Wk, Wv).
__global__ __launch_bounds__(256) void cast4_kernel(
  const float* __restrict__ s0, unsigned short* __restrict__ d0, int n0,
  const float* __restrict__ s1, unsigned short* __restrict__ d1, int n1,
  const float* __restrict__ s2, unsigned short* __restrict__ d2, int n2,
  const float* __restrict__ s3, unsigned short* __restrict__ d3, int n3)
{
  const int total = n0 + n1 + n2 + n3;
  const int stride = gridDim.x * blockDim.x;
  for (int i = blockIdx.x*blockDim.x + threadIdx.x; i < total; i += stride){
    const float* s; unsigned short* d; int j = i;
    if (j < n0) { s = s0; d = d0; }
    else { j -= n0;
      if (j < n1) { s = s1; d = d1; }
      else { j -= n1;
        if (j < n2) { s = s2; d = d2; }
        else { j -= n2; s = s3; d = d3; } } }
    float4 v = reinterpret_cast<const float4*>(s)[j];
    short4 o;
    o.x = (short)f2bf(v.x); o.y = (short)f2bf(v.y);
    o.z = (short)f2bf(v.z); o.w = (short)f2bf(v.w);
    reinterpret_cast<short4*>(d)[j] = o;
  }
}

__global__ __launch_bounds__(256) void cast_bf16_kernel(const float* __restrict__ in,
                                                        unsigned short* __restrict__ out, int n4){
  const int stride = gridDim.x * blockDim.x;
  for (int i = blockIdx.x*blockDim.x + threadIdx.x; i < n4; i += stride){
    float4 v = reinterpret_cast<const float4*>(in)[i];
    short4 o;
    o.x = (short)f2bf(v.x); o.y = (short)f2bf(v.y);
    o.z = (short)f2bf(v.z); o.w = (short)f2bf(v.w);
    reinterpret_cast<short4*>(out)[i] = o;
  }
}

// ---------------------------------------------------------------------------
// Fused QKV 256x256 8-phase GEMM: grid.x 0..13 -> Q tiles (Wq), 14..15 -> K
// (Wk), 16..17 -> V (Wv, transposed epilogue). Main loop identical to the
// verified gemm256; only block-uniform B-select + epilogue differ.
// ---------------------------------------------------------------------------
__global__ __launch_bounds__(512, 2) void qkv256(
  const unsigned short* __restrict__ Aq,
  const unsigned short* __restrict__ Wq,
  const unsigned short* __restrict__ Wk,
  const unsigned short* __restrict__ Wv,
  const float* __restrict__ bq, const float* __restrict__ bk, const float* __restrict__ bv,
  unsigned short* __restrict__ Qp, unsigned short* __restrict__ Kp, unsigned short* __restrict__ Vt)
{
  __shared__ unsigned short As[2][16384];
  __shared__ unsigned short Bs[2][16384];
  const int tid = threadIdx.x;
  const int w = tid >> 6, l = tid & 63;
  const int l15 = l & 15, g = l >> 4;
  const int wr = w >> 2, wc = w & 3;
  const int nx = blockIdx.x;
  const int tm = blockIdx.y * 256;

  const unsigned short* Wt; const float* bias; int tnl, mode;
  if (nx < 14)      { Wt = Wq; bias = bq; tnl = nx*256;      mode = 0; }
  else if (nx < 16) { Wt = Wk; bias = bk; tnl = (nx-14)*256; mode = 1; }
  else              { Wt = Wv; bias = bv; tnl = (nx-16)*256; mode = 2; }

  const f32x4 z = {0.f,0.f,0.f,0.f};
  f32x4 acc[8][4];
  #pragma unroll
  for (int i=0;i<8;i++)
    #pragma unroll
    for (int j=0;j<4;j++) acc[i][j] = z;

  const int srow = w*8 + (l >> 3);
  const int scol = ((l & 7) ^ (l >> 3)) * 8;
  const unsigned short* Ab = Aq + (size_t)(tm + srow) * Dn + scol;
  const unsigned short* Bb = Wt + (size_t)(tnl + srow) * Dn + scol;

#define STG256(PTR, DS, KO, BUF) do { unsigned short* d_ = &DS[BUF][w*512]; \
    glds16(PTR + (KO),                    d_);          \
    glds16(PTR + (size_t) 64*Dn + (KO),   d_ + 4096);   \
    glds16(PTR + (size_t)128*Dn + (KO),   d_ + 8192);   \
    glds16(PTR + (size_t)192*Dn + (KO),   d_ + 12288); } while(0)

  const int nkt = Dn / 64;   // 56
  STG256(Ab, As, 0, 0);
  STG256(Bb, Bs, 0, 0);
  asm volatile("s_waitcnt vmcnt(0)" ::: "memory");
  __builtin_amdgcn_s_barrier();

  const int swz = (l15 & 7) << 3;
  bf16x8 bfr[4], af[4];

  for (int t = 0; t < nkt; ++t) {
    const unsigned short* Asb = &As[t & 1][0];
    const unsigned short* Bsb = &Bs[t & 1][0];
    const int nko = (t + 1) * 64;
    const bool pf = (t + 1 < nkt);
    const int nbuf = (t + 1) & 1;

    #pragma unroll
    for (int ni=0; ni<4; ni++)
      bfr[ni] = *reinterpret_cast<const bf16x8*>(&Bsb[(((wc*64 + ni*16 + l15)*64) + g*8) ^ swz]);
    #pragma unroll
    for (int mi=0; mi<4; mi++)
      af[mi] = *reinterpret_cast<const bf16x8*>(&Asb[(((wr*128 + mi*16 + l15)*64) + g*8) ^ swz]);
    if (pf) STG256(Ab, As, nko, nbuf);
    __builtin_amdgcn_s_barrier();
    asm volatile("s_waitcnt lgkmcnt(0)" ::: "memory");
    __builtin_amdgcn_sched_barrier(0);
    __builtin_amdgcn_s_setprio(1);
    #pragma unroll
    for (int mi=0; mi<4; mi++)
      #pragma unroll
      for (int ni=0; ni<4; ni++)
        acc[mi][ni] = __builtin_amdgcn_mfma_f32_16x16x32_bf16(af[mi], bfr[ni], acc[mi][ni], 0,0,0);
    __builtin_amdgcn_s_setprio(0);
    __builtin_amdgcn_s_barrier();

    #pragma unroll
    for (int mi=0; mi<4; mi++)
      af[mi] = *reinterpret_cast<const bf16x8*>(&Asb[(((wr*128 + (mi+4)*16 + l15)*64) + g*8) ^ swz]);
    if (pf) STG256(Bb, Bs, nko, nbuf);
    __builtin_amdgcn_s_barrier();
    asm volatile("s_waitcnt lgkmcnt(0)" ::: "memory");
    __builtin_amdgcn_sched_barrier(0);
    __builtin_amdgcn_s_setprio(1);
    #pragma unroll
    for (int mi=0; mi<4; mi++)
      #pragma unroll
      for (int ni=0; ni<4; ni++)
        acc[mi+4][ni] = __builtin_amdgcn_mfma_f32_16x16x32_bf16(af[mi], bfr[ni], acc[mi+4][ni], 0,0,0);
    __builtin_amdgcn_s_setprio(0);
    __builtin_amdgcn_s_barrier();

    #pragma unroll
    for (int ni=0; ni<4; ni++)
      bfr[ni] = *reinterpret_cast<const bf16x8*>(&Bsb[(((wc*64 + ni*16 + l15)*64) + 32 + g*8) ^ swz]);
    #pragma unroll
    for (int mi=0; mi<4; mi++)
      af[mi] = *reinterpret_cast<const bf16x8*>(&Asb[(((wr*128 + mi*16 + l15)*64) + 32 + g*8) ^ swz]);
    __builtin_amdgcn_s_barrier();
    asm volatile("s_waitcnt lgkmcnt(0)" ::: "memory");
    __builtin_amdgcn_sched_barrier(0);
    __builtin_amdgcn_s_setprio(1);
    #pragma unroll
    for (int mi=0; mi<4; mi++)
      #pragma unroll
      for (int ni=0; ni<4; ni++)
        acc[mi][ni] = __builtin_amdgcn_mfma_f32_16x16x32_bf16(af[mi], bfr[ni], acc[mi][ni], 0,0,0);
    __builtin_amdgcn_s_setprio(0);
    __builtin_amdgcn_s_barrier();

    #pragma unroll
    for (int mi=0; mi<4; mi++)
      af[mi] = *reinterpret_cast<const bf16x8*>(&Asb[(((wr*128 + (mi+4)*16 + l15)*64) + 32 + g*8) ^ swz]);
    __builtin_amdgcn_s_barrier();
    asm volatile("s_waitcnt lgkmcnt(0)" ::: "memory");
    __builtin_amdgcn_sched_barrier(0);
    __builtin_amdgcn_s_setprio(1);
    #pragma unroll
    for (int mi=0; mi<4; mi++)
      #pragma unroll
      for (int ni=0; ni<4; ni++)
        acc[mi+4][ni] = __builtin_amdgcn_mfma_f32_16x16x32_bf16(af[mi], bfr[ni], acc[mi+4][ni], 0,0,0);
    __builtin_amdgcn_s_setprio(0);
    asm volatile("s_waitcnt vmcnt(0)" ::: "memory");
    __builtin_amdgcn_s_barrier();
  }
#undef STG256

  // epilogue (block-uniform mode)
  #pragma unroll
  for (int mi=0; mi<8; mi++){
    #pragma unroll
    for (int ni=0; ni<4; ni++){
      const int cl = wc*64 + ni*16 + l15;        // 0..255 within tile
      const int row0 = tm + wr*128 + mi*16 + g*4;
      const float bb = bias[tnl + cl];
      if (mode == 0) {
        #pragma unroll
        for (int r=0;r<4;r++)
          Qp[(size_t)(row0+r)*Dn + tnl + cl] = f2bf(acc[mi][ni][r] + bb);
      } else if (mode == 1) {
        #pragma unroll
        for (int r=0;r<4;r++)
          Kp[(size_t)(row0+r)*512 + tnl + cl] = f2bf(acc[mi][ni][r] + bb);
      } else {
        const int dcol = tnl + cl;               // 0..511 within V
        const int b = row0 >> 11, sbase = row0 & 2047;
        ushort4 pk;
        pk.x = f2bf(acc[mi][ni][0] + bb);
        pk.y = f2bf(acc[mi][ni][1] + bb);
        pk.z = f2bf(acc[mi][ni][2] + bb);
        pk.w = f2bf(acc[mi][ni][3] + bb);
        *reinterpret_cast<ushort4*>(
          &Vt[(((size_t)b*KVn + (dcol>>7))*HDn + (dcol&127))*Sn + sbase]) = pk;
      }
    }
  }
}

// ---------------------------------------------------------------------------
// 256x256 8-phase GEMM for the O-projection (fp32 out). Unchanged from R11.
// ---------------------------------------------------------------------------
__global__ __launch_bounds__(512, 2) void o_gemm256(
  const unsigned short* __restrict__ Aq,
  const unsigned short* __restrict__ Wt,
  float* __restrict__ OutF)
{
  __shared__ unsigned short As[2][16384];
  __shared__ unsigned short Bs[2][16384];
  const int tid = threadIdx.x;
  const int w = tid >> 6, l = tid & 63;
  const int l15 = l & 15, g = l >> 4;
  const int wr = w >> 2, wc = w & 3;
  const int tn = blockIdx.x * 256;
  const int tm = blockIdx.y * 256;

  const f32x4 z = {0.f,0.f,0.f,0.f};
  f32x4 acc[8][4];
  #pragma unroll
  for (int i=0;i<8;i++)
    #pragma unroll
    for (int j=0;j<4;j++) acc[i][j] = z;

  const int srow = w*8 + (l >> 3);
  const int scol = ((l & 7) ^ (l >> 3)) * 8;
  const unsigned short* Ab = Aq + (size_t)(tm + srow) * Dn + scol;
  const unsigned short* Bb = Wt + (size_t)(tn + srow) * Dn + scol;

#define STG256(PTR, DS, KO, BUF) do { unsigned short* d_ = &DS[BUF][w*512]; \
    glds16(PTR + (KO),                    d_);          \
    glds16(PTR + (size_t) 64*Dn + (KO),   d_ + 4096);   \
    glds16(PTR + (size_t)128*Dn + (KO),   d_ + 8192);   \
    glds16(PTR + (size_t)192*Dn + (KO),   d_ + 12288); } while(0)

  const int nkt = Dn / 64;   // 56
  STG256(Ab, As, 0, 0);
  STG256(Bb, Bs, 0, 0);
  asm volatile("s_waitcnt vmcnt(0)" ::: "memory");
  __builtin_amdgcn_s_barrier();

  const int swz = (l15 & 7) << 3;
  bf16x8 bfr[4], af[4];

  for (int t = 0; t < nkt; ++t) {
    const unsigned short* Asb = &As[t & 1][0];
    const unsigned short* Bsb = &Bs[t & 1][0];
    const int nko = (t + 1) * 64;
    const bool pf = (t + 1 < nkt);
    const int nbuf = (t + 1) & 1;

    #pragma unroll
    for (int ni=0; ni<4; ni++)
      bfr[ni] = *reinterpret_cast<const bf16x8*>(&Bsb[(((wc*64 + ni*16 + l15)*64) + g*8) ^ swz]);
    #pragma unroll
    for (int mi=0; mi<4; mi++)
      af[mi] = *reinterpret_cast<const bf16x8*>(&Asb[(((wr*128 + mi*16 + l15)*64) + g*8) ^ swz]);
    if (pf) STG256(Ab, As, nko, nbuf);
    __builtin_amdgcn_s_barrier();
    asm volatile("s_waitcnt lgkmcnt(0)" ::: "memory");
    __builtin_amdgcn_sched_barrier(0);
    __builtin_amdgcn_s_setprio(1);
    #pragma unroll
    for (int mi=0; mi<4; mi++)
      #pragma unroll
      for (int ni=0; ni<4; ni++)
        acc[mi][ni] = __builtin_amdgcn_mfma_f32_16x16x32_bf16(af[mi], bfr[ni], acc[mi][ni], 0,0,0);
    __builtin_amdgcn_s_setprio(0);
    __builtin_amdgcn_s_barrier();

    #pragma unroll
    for (int mi=0; mi<4; mi++)
      af[mi] = *reinterpret_cast<const bf16x8*>(&Asb[(((wr*128 + (mi+4)*16 + l15)*64) + g*8) ^ swz]);
    if (pf) STG256(Bb, Bs, nko, nbuf);
    __builtin_amdgcn_s_barrier();
    asm volatile("s_waitcnt lgkmcnt(0)" ::: "memory");
    __builtin_amdgcn_sched_barrier(0);
    __builtin_amdgcn_s_setprio(1);
    #pragma unroll
    for (int mi=0; mi<4; mi++)
      #pragma unroll
      for (int ni=0; ni<4; ni++)
        acc[mi+4][ni] = __builtin_amdgcn_mfma_f32_16x16x32_bf16(af[mi], bfr[ni], acc[mi+4][ni], 0,0,0);
    __builtin_amdgcn_s_setprio(0);
    __builtin_amdgcn_s_barrier();

    #pragma unroll
    for (int ni=0; ni<4; ni++)
      bfr[ni] = *reinterpret_cast<const bf16x8*>(&Bsb[(((wc*64 + ni*16 + l15)*64) + 32 + g*8) ^ swz]);
    #pragma unroll
    for (int mi=0; mi<4; mi++)
      af[mi] = *reinterpret_cast<const bf16x8*>(&Asb[(((wr*128 + mi*16 + l15)*64) + 32 + g*8) ^ swz]);
    __builtin_amdgcn_s_barrier();
    asm volatile("s_waitcnt lgkmcnt(0)" ::: "memory");
    __builtin_amdgcn_sched_barrier(0);
    __builtin_amdgcn_s_setprio(1);
    #pragma unroll
    for (int mi=0; mi<4; mi++)
      #pragma unroll
      for (int ni=0; ni<4; ni++)
        acc[mi][ni] = __builtin_amdgcn_mfma_f32_16x16x32_bf16(af[mi], bfr[ni], acc[mi][ni], 0,0,0);
    __builtin_amdgcn_s_setprio(0);
    __builtin_amdgcn_s_barrier();

    #pragma unroll
    for (int mi=0; mi<4; mi++)
      af[mi] = *reinterpret_cast<const bf16x8*>(&Asb[(((wr*128 + (mi+4)*16 + l15)*64) + 32 + g*8) ^ swz]);
    __builtin_amdgcn_s_barrier();
    asm volatile("s_waitcnt lgkmcnt(0)" ::: "memory");
    __builtin_amdgcn_sched_barrier(0);
    __builtin_amdgcn_s_setprio(1);
    #pragma unroll
    for (int mi=0; mi<4; mi++)
      #pragma unroll
      for (int ni=0; ni<4; ni++)
        acc[mi+4][ni] = __builtin_amdgcn_mfma_f32_16x16x32_bf16(af[mi], bfr[ni], acc[mi+4][ni], 0,0,0);
    __builtin_amdgcn_s_setprio(0);
    asm volatile("s_waitcnt vmcnt(0)" ::: "memory");
    __builtin_amdgcn_s_barrier();
  }
#undef STG256

  #pragma unroll
  for (int mi=0; mi<8; mi++)
    #pragma unroll
    for (int ni=0; ni<4; ni++){
      const int cl = tn + wc*64 + ni*16 + l15;
      const int row0 = tm + wr*128 + mi*16 + g*4;
      #pragma unroll
      for (int r=0;r<4;r++)
        OutF[(size_t)(row0+r)*Dn + cl] = acc[mi][ni][r];
    }
}

// RoPE + relayout, vectorized. K outputs pre-scaled by k2 = SCALING*log2e.
__global__ __launch_bounds__(256) void rope_kernel(
  const unsigned short* __restrict__ Qp, const unsigned short* __restrict__ Kp,
  const float* __restrict__ cosp, const float* __restrict__ sinp,
  unsigned short* __restrict__ Qh, unsigned short* __restrict__ Kh)
{
  const int t = threadIdx.x;
  const int bs = blockIdx.x;
  const int head = t >> 3;
  const int d0 = (t & 7) * 8;
  const int b = bs >> 11, s = bs & 2047;

  const float* cp = cosp + (size_t)bs*128;
  const float* sp = sinp + (size_t)bs*128;
  float4 cA0 = *reinterpret_cast<const float4*>(cp + d0);
  float4 cA1 = *reinterpret_cast<const float4*>(cp + d0 + 4);
  float4 cB0 = *reinterpret_cast<const float4*>(cp + d0 + 64);
  float4 cB1 = *reinterpret_cast<const float4*>(cp + d0 + 68);
  float4 sA0 = *reinterpret_cast<const float4*>(sp + d0);
  float4 sA1 = *reinterpret_cast<const float4*>(sp + d0 + 4);
  float4 sB0 = *reinterpret_cast<const float4*>(sp + d0 + 64);
  float4 sB1 = *reinterpret_cast<const float4*>(sp + d0 + 68);

  const unsigned short* src; unsigned short* dst; float kscale;
  if (head < Hn) {
    src = Qp + (size_t)bs*Dn + head*HDn;
    dst = Qh + (((size_t)b*Hn + head)*Sn + s)*HDn;
    kscale = 1.0f;
  } else {
    const int kvh = head - Hn;
    src = Kp + (size_t)bs*512 + kvh*HDn;
    dst = Kh + (((size_t)b*KVn + kvh)*Sn + s)*HDn;
    kscale = 0.08838834764831845f * 1.4426950408889634f;
  }

  union { int4 v; unsigned short u[8]; } lo, hi, olo, ohi;
  lo.v = *reinterpret_cast<const int4*>(src + d0);
  hi.v = *reinterpret_cast<const int4*>(src + d0 + 64);
  #pragma unroll
  for (int j=0;j<8;j++){
    const float ca = (j<4)? (&cA0.x)[j] : (&cA1.x)[j-4];
    const float cb = (j<4)? (&cB0.x)[j] : (&cB1.x)[j-4];
    const float sa = (j<4)? (&sA0.x)[j] : (&sA1.x)[j-4];
    const float sb = (j<4)? (&sB0.x)[j] : (&sB1.x)[j-4];
    const float x0 = bf2f(lo.u[j]), x1 = bf2f(hi.u[j]);
    olo.u[j] = f2bf((x0*ca - x1*sa) * kscale);
    ohi.u[j] = f2bf((x1*cb + x0*sb) * kscale);
  }
  *reinterpret_cast<int4*>(dst + d0)      = olo.v;
  *reinterpret_cast<int4*>(dst + d0 + 64) = ohi.v;
}

// Flash attention: R19 structure (best measured). Unchanged.
__global__ __launch_bounds__(256, 3) void attn_kernel(
  const unsigned short* __restrict__ Qh,
  const unsigned short* __restrict__ Kh,
  const unsigned short* __restrict__ Vt,
  unsigned short* __restrict__ ctx)
{
  __shared__ unsigned short Klds[64*136];
  __shared__ unsigned short Vlds[128*72];
  __shared__ __bf16 Plds[4][16*72];

  const int tid = threadIdx.x, w = tid>>6, l = tid&63;
  const int l15 = l&15, g = l>>4;
  const int bh = blockIdx.x;
  const int qt = (int)gridDim.y - 1 - (int)blockIdx.y;
  const int b = bh / Hn, h = bh % Hn;
  const int kv = h / 7;
  const int qbase = qt * 64;
  const size_t qoff = ((size_t)b*Hn + h) * Sn;
  const size_t koff = ((size_t)b*KVn + kv) * Sn;
  const unsigned short* Kg0 = Kh + koff*HDn;
  const unsigned short* Vg0 = Vt + ((size_t)b*KVn + kv)*HDn*Sn;

  bf16x8 qf[4];
  {
    const int qrow = qbase + w*16 + l15;
    #pragma unroll
    for (int st=0; st<4; st++)
      qf[st] = *reinterpret_cast<const bf16x8*>(Qh + (qoff + qrow)*HDn + st*32 + g*8);
  }

  const f32x4 z = {0.f,0.f,0.f,0.f};
  f32x4 o[8];
  #pragma unroll
  for (int dc=0; dc<8; dc++) o[dc] = z;
  f32x4 ls = z;
  float m_[4];
  #pragma unroll
  for (int r=0;r<4;r++) m_[r] = -1e30f;

  const bf16x8 onesv = {(__bf16)1.f,(__bf16)1.f,(__bf16)1.f,(__bf16)1.f,
                        (__bf16)1.f,(__bf16)1.f,(__bf16)1.f,(__bf16)1.f};

  const int k_r  = tid >> 4;
  const int k_c  = (tid & 15) * 8;
  const int v_d  = tid >> 3;
  const int v_s  = (tid & 7) * 8;

  const unsigned short* Kgp = Kg0 + (size_t)k_r*HDn + k_c;
  const unsigned short* Vgp = Vg0 + (size_t)v_d*Sn + v_s;

  int4 ka, kb, kc4, kd, va, vb, vc4, vd;

#define PREFETCH(KT) do {                                                     \
    const unsigned short* Kg_ = Kgp + (size_t)(KT)*64*HDn;                    \
    const unsigned short* Vg_ = Vgp + (size_t)(KT)*64;                        \
    ka  = *reinterpret_cast<const int4*>(Kg_);                                \
    kb  = *reinterpret_cast<const int4*>(Kg_ + 16*HDn);                       \
    kc4 = *reinterpret_cast<const int4*>(Kg_ + 32*HDn);                       \
    kd  = *reinterpret_cast<const int4*>(Kg_ + 48*HDn);                       \
    va  = *reinterpret_cast<const int4*>(Vg_);                                \
    vb  = *reinterpret_cast<const int4*>(Vg_ + (size_t)32*Sn);                \
    vc4 = *reinterpret_cast<const int4*>(Vg_ + (size_t)64*Sn);                \
    vd  = *reinterpret_cast<const int4*>(Vg_ + (size_t)96*Sn);                \
  } while(0)

  const int nkt = qt + 1;
  PREFETCH(0);

  for (int kt = 0; kt < nkt; kt++) {
    __syncthreads();
    *reinterpret_cast<int4*>(&Klds[(k_r     )*136 + k_c]) = ka;
    *reinterpret_cast<int4*>(&Klds[(k_r + 16)*136 + k_c]) = kb;
    *reinterpret_cast<int4*>(&Klds[(k_r + 32)*136 + k_c]) = kc4;
    *reinterpret_cast<int4*>(&Klds[(k_r + 48)*136 + k_c]) = kd;
    *reinterpret_cast<int4*>(&Vlds[(v_d     )*72 + v_s]) = va;
    *reinterpret_cast<int4*>(&Vlds[(v_d + 32)*72 + v_s]) = vb;
    *reinterpret_cast<int4*>(&Vlds[(v_d + 64)*72 + v_s]) = vc4;
    *reinterpret_cast<int4*>(&Vlds[(v_d + 96)*72 + v_s]) = vd;
    if (kt + 1 < nkt) PREFETCH(kt + 1);
    __syncthreads();

    // S = Q (k2*K)^T  — already in exp2 domain
    f32x4 sa[4];
    #pragma unroll
    for (int hc=0; hc<4; hc++) sa[hc] = z;
    __builtin_amdgcn_s_setprio(1);
    #pragma unroll
    for (int hc=0; hc<4; hc++){
      #pragma unroll
      for (int st=0; st<4; st++){
        const bf16x8 kf = *reinterpret_cast<const bf16x8*>(&Klds[(hc*16 + l15)*136 + st*32 + g*8]);
        sa[hc] = __builtin_amdgcn_mfma_f32_16x16x32_bf16(qf[st], kf, sa[hc], 0,0,0);
      }
    }
    __builtin_amdgcn_s_setprio(0);
    // causal mask: only the diagonal tile
    const int q0 = qbase + w*16 + g*4;
    if (kt == qt) {
      #pragma unroll
      for (int hc=0; hc<4; hc++){
        const int kc = kt*64 + hc*16 + l15;
        #pragma unroll
        for (int r=0;r<4;r++)
          sa[hc][r] = (kc <= q0 + r) ? sa[hc][r] : -1e30f;
      }
    }
    // online softmax: DPP max reduce; denominator on the matrix pipe
    f32x4 sfv;
    #pragma unroll
    for (int r=0;r<4;r++){
      float mx = fmaxf(fmaxf(sa[0][r], sa[1][r]), fmaxf(sa[2][r], sa[3][r]));
      mx = fmaxf(mx, dppf<0x128>(mx));
      mx = fmaxf(mx, dppf<0x124>(mx));
      mx = fmaxf(mx, dppf<0x122>(mx));
      mx = fmaxf(mx, dppf<0x121>(mx));
      const float mn = fmaxf(m_[r], mx);
      sfv[r] = exp2f(m_[r] - mn);
      m_[r] = mn;
    }
    #pragma unroll
    for (int hc=0; hc<4; hc++)
      #pragma unroll
      for (int r=0;r<4;r++)
        sa[hc][r] = exp2f(sa[hc][r] - m_[r]);
    #pragma unroll
    for (int dc=0; dc<8; dc++) o[dc] *= sfv;
    ls *= sfv;
    // P -> per-wave LDS -> A-fragments
    #pragma unroll
    for (int hc=0; hc<4; hc++)
      #pragma unroll
      for (int r=0;r<4;r++)
        Plds[w][(g*4+r)*72 + hc*16 + l15] = (__bf16)sa[hc][r];
    bf16x8 pf[2];
    pf[0] = *reinterpret_cast<const bf16x8*>(&Plds[w][l15*72 + g*8]);
    pf[1] = *reinterpret_cast<const bf16x8*>(&Plds[w][l15*72 + 32 + g*8]);
    // denominator + PV on the matrix pipe
    __builtin_amdgcn_s_setprio(1);
    ls = __builtin_amdgcn_mfma_f32_16x16x32_bf16(pf[0], onesv, ls, 0,0,0);
    ls = __builtin_amdgcn_mfma_f32_16x16x32_bf16(pf[1], onesv, ls, 0,0,0);
    #pragma unroll
    for (int dc=0; dc<8; dc++){
      #pragma unroll
      for (int ks=0; ks<2; ks++){
        const bf16x8 vf = *reinterpret_cast<const bf16x8*>(&Vlds[(dc*16 + l15)*72 + ks*32 + g*8]);
        o[dc] = __builtin_amdgcn_mfma_f32_16x16x32_bf16(pf[ks], vf, o[dc], 0,0,0);
      }
    }
    __builtin_amdgcn_s_setprio(0);
  }
#undef PREFETCH

  f32x4 linv;
  #pragma unroll
  for (int r=0;r<4;r++) linv[r] = 1.0f / ls[r];
  const int s0r = qbase + w*16 + g*4;
  #pragma unroll
  for (int dc=0; dc<8; dc++)
    #pragma unroll
    for (int r=0;r<4;r++)
      ctx[((size_t)b*Sn + s0r + r)*Dn + h*HDn + dc*16 + l15] = f2bf(o[dc][r] * linv[r]);
}

extern "C" void kernel_launch(void* const* d_in, const int* in_sizes, int n_in,
                              void* d_out, int out_size, void* d_ws, size_t ws_size,
                              hipStream_t stream)
{
  (void)in_sizes; (void)n_in; (void)out_size; (void)ws_size;
  const float* hidden = (const float*)d_in[0];
  const float* cosp   = (const float*)d_in[1];
  const float* sinp   = (const float*)d_in[2];
  // d_in[3] = attention_mask: pure causal by construction -> applied analytically
  const float* wq = (const float*)d_in[4];
  const float* bq = (const float*)d_in[5];
  const float* wk = (const float*)d_in[6];
  const float* bk = (const float*)d_in[7];
  const float* wv = (const float*)d_in[8];
  const float* bv = (const float*)d_in[9];
  const float* wo = (const float*)d_in[10];

  char* ws = (char*)d_ws;
  const size_t nX  = (size_t)Bn*Sn*Dn;       // 14,680,064
  const size_t nWq = (size_t)Hn*HDn*Dn;      // 12,845,056
  const size_t nWk = (size_t)KVn*HDn*Dn;     //  1,835,008
  const size_t nKV = (size_t)Bn*KVn*Sn*HDn;  //  2,097,152

  unsigned short* Xb  = (unsigned short*)(ws);                                   // -> reused as Qh
  unsigned short* Wqb = (unsigned short*)(ws + 2*nX);                            // -> reused as Wob
  unsigned short* Wkb = (unsigned short*)(ws + 2*(nX + nWq));
  unsigned short* Wvb = (unsigned short*)(ws + 2*(nX + nWq + nWk));
  unsigned short* Qp  = (unsigned short*)(ws + 2*(nX + nWq + 2*nWk));            // -> reused as ctx
  unsigned short* Kp  = (unsigned short*)(ws + 2*(2*nX + nWq + 2*nWk));
  unsigned short* Kh  = (unsigned short*)(ws + 2*(2*nX + nWq + 2*nWk + nKV));
  unsigned short* Vt  = (unsigned short*)(ws + 2*(2*nX + nWq + 2*nWk + 2*nKV));

  // fused pre-casts: X, Wq, Wk, Wv in one launch
  cast4_kernel<<<dim3(2048), dim3(256), 0, stream>>>(
      hidden, Xb,  (int)(nX/4),
      wq,     Wqb, (int)(nWq/4),
      wk,     Wkb, (int)(nWk/4),
      wv,     Wvb, (int)(nWk/4));

  // fused Q+K+V projection (18x16 = 288 blocks, one residency round @2/CU)
  qkv256<<<dim3(18, 16), dim3(512), 0, stream>>>(Xb, Wqb, Wkb, Wvb, bq, bk, bv, Qp, Kp, Vt);

  {
    int n4 = (int)(nWq/4);
    cast_bf16_kernel<<<dim3(4096), dim3(256), 0, stream>>>(wo, Wqb, n4);  // Wob reuses Wqb
  }

  rope_kernel<<<dim3(Bn*Sn), dim3(256), 0, stream>>>(Qp, Kp, cosp, sinp, /*Qh=*/Xb, Kh);

  attn_kernel<<<dim3(Bn*Hn, Sn/64), dim3(256), 0, stream>>>(/*Qh=*/Xb, Kh, Vt, /*ctx=*/Qp);

  o_gemm256<<<dim3(Dn/256, (Bn*Sn)/256), dim3(512), 0, stream>>>(/*ctx=*/Qp, /*Wob=*/Wqb, (float*)d_out);
}

// Round 21
// 424.735 us; speedup vs baseline: 1.1007x; 1.1007x over previous
//
#include <hip/hip_runtime.h>
#include <stdint.h>

#define Bn 2
#define Sn 2048
#define Dn 3584
#define Hn 28
#define KVn 4
#define HDn 128

typedef __bf16 bf16x8 __attribute__((ext_vector_type(8)));
typedef float f32x4 __attribute__((ext_vector_type(4)));

__device__ __forceinline__ unsigned short f2bf(float f){
  union { float f; unsigned u; } a; a.f = f;
  unsigned r = a.u + 0x7fffu + ((a.u >> 16) & 1u);
  return (unsigned short)(r >> 16);
}
__device__ __forceinline__ float bf2f(unsigned short s){
  union { unsigned u; float f; } a; a.u = ((unsigned)s) << 16; return a.f;
}

// DPP row-rotate (16-lane row), full-rate VALU cross-lane.
template<int CTRL>
__device__ __forceinline__ float dppf(float x){
  return __int_as_float(__builtin_amdgcn_update_dpp(0, __float_as_int(x), CTRL, 0xf, 0xf, true));
}

// global -> LDS direct copy, 16B per lane. lds must be wave-uniform; HW adds lane*16.
__device__ __forceinline__ void glds16(const unsigned short* g, const unsigned short* lds){
  __builtin_amdgcn_global_load_lds(
      (const __attribute__((address_space(1))) void*)(uintptr_t)g,
      (__attribute__((address_space(3))) void*)(uintptr_t)lds,
      16, 0, 0);
}

// Fused 4-segment fp32->bf16 cast (one launch for X, Wq, Wk, Wv).
__global__ __launch_bounds__(256) void cast4_kernel(
  const float* __restrict__ s0, unsigned short* __restrict__ d0, int n0,
  const float* __restrict__ s1, unsigned short* __restrict__ d1, int n1,
  const float* __restrict__ s2, unsigned short* __restrict__ d2, int n2,
  const float* __restrict__ s3, unsigned short* __restrict__ d3, int n3)
{
  const int total = n0 + n1 + n2 + n3;
  const int stride = gridDim.x * blockDim.x;
  for (int i = blockIdx.x*blockDim.x + threadIdx.x; i < total; i += stride){
    const float* s; unsigned short* d; int j = i;
    if (j < n0) { s = s0; d = d0; }
    else { j -= n0;
      if (j < n1) { s = s1; d = d1; }
      else { j -= n1;
        if (j < n2) { s = s2; d = d2; }
        else { j -= n2; s = s3; d = d3; } } }
    float4 v = reinterpret_cast<const float4*>(s)[j];
    short4 o;
    o.x = (short)f2bf(v.x); o.y = (short)f2bf(v.y);
    o.z = (short)f2bf(v.z); o.w = (short)f2bf(v.w);
    reinterpret_cast<short4*>(d)[j] = o;
  }
}

__global__ __launch_bounds__(256) void cast_bf16_kernel(const float* __restrict__ in,
                                                        unsigned short* __restrict__ out, int n4){
  const int stride = gridDim.x * blockDim.x;
  for (int i = blockIdx.x*blockDim.x + threadIdx.x; i < n4; i += stride){
    float4 v = reinterpret_cast<const float4*>(in)[i];
    short4 o;
    o.x = (short)f2bf(v.x); o.y = (short)f2bf(v.y);
    o.z = (short)f2bf(v.z); o.w = (short)f2bf(v.w);
    reinterpret_cast<short4*>(out)[i] = o;
  }
}

// ---------------------------------------------------------------------------
// 256x256 8-phase GEMM (m201 template, plain HIP). R11-verified.
// ---------------------------------------------------------------------------
template<int OUTMODE>
__global__ __launch_bounds__(512, 2) void gemm256(
  const unsigned short* __restrict__ Aq,
  const unsigned short* __restrict__ Wt,
  const float* __restrict__ bias,
  unsigned short* __restrict__ OutB,
  float* __restrict__ OutF)
{
  __shared__ unsigned short As[2][16384];
  __shared__ unsigned short Bs[2][16384];
  const int tid = threadIdx.x;
  const int w = tid >> 6, l = tid & 63;
  const int l15 = l & 15, g = l >> 4;
  const int wr = w >> 2, wc = w & 3;
  const int tn = blockIdx.x * 256;
  const int tm = blockIdx.y * 256;

  const f32x4 z = {0.f,0.f,0.f,0.f};
  f32x4 acc[8][4];
  #pragma unroll
  for (int i=0;i<8;i++)
    #pragma unroll
    for (int j=0;j<4;j++) acc[i][j] = z;

  const int srow = w*8 + (l >> 3);
  const int scol = ((l & 7) ^ (l >> 3)) * 8;
  const unsigned short* Ab = Aq + (size_t)(tm + srow) * Dn + scol;
  const unsigned short* Bb = Wt + (size_t)(tn + srow) * Dn + scol;

#define STG256(PTR, DS, KO, BUF) do { unsigned short* d_ = &DS[BUF][w*512]; \
    glds16(PTR + (KO),                    d_);          \
    glds16(PTR + (size_t) 64*Dn + (KO),   d_ + 4096);   \
    glds16(PTR + (size_t)128*Dn + (KO),   d_ + 8192);   \
    glds16(PTR + (size_t)192*Dn + (KO),   d_ + 12288); } while(0)

  const int nkt = Dn / 64;   // 56
  STG256(Ab, As, 0, 0);
  STG256(Bb, Bs, 0, 0);
  asm volatile("s_waitcnt vmcnt(0)" ::: "memory");
  __builtin_amdgcn_s_barrier();

  const int swz = (l15 & 7) << 3;
  bf16x8 bfr[4], af[4];

  for (int t = 0; t < nkt; ++t) {
    const unsigned short* Asb = &As[t & 1][0];
    const unsigned short* Bsb = &Bs[t & 1][0];
    const int nko = (t + 1) * 64;
    const bool pf = (t + 1 < nkt);
    const int nbuf = (t + 1) & 1;

    #pragma unroll
    for (int ni=0; ni<4; ni++)
      bfr[ni] = *reinterpret_cast<const bf16x8*>(&Bsb[(((wc*64 + ni*16 + l15)*64) + g*8) ^ swz]);
    #pragma unroll
    for (int mi=0; mi<4; mi++)
      af[mi] = *reinterpret_cast<const bf16x8*>(&Asb[(((wr*128 + mi*16 + l15)*64) + g*8) ^ swz]);
    if (pf) STG256(Ab, As, nko, nbuf);
    __builtin_amdgcn_s_barrier();
    asm volatile("s_waitcnt lgkmcnt(0)" ::: "memory");
    __builtin_amdgcn_sched_barrier(0);
    __builtin_amdgcn_s_setprio(1);
    #pragma unroll
    for (int mi=0; mi<4; mi++)
      #pragma unroll
      for (int ni=0; ni<4; ni++)
        acc[mi][ni] = __builtin_amdgcn_mfma_f32_16x16x32_bf16(af[mi], bfr[ni], acc[mi][ni], 0,0,0);
    __builtin_amdgcn_s_setprio(0);
    __builtin_amdgcn_s_barrier();

    #pragma unroll
    for (int mi=0; mi<4; mi++)
      af[mi] = *reinterpret_cast<const bf16x8*>(&Asb[(((wr*128 + (mi+4)*16 + l15)*64) + g*8) ^ swz]);
    if (pf) STG256(Bb, Bs, nko, nbuf);
    __builtin_amdgcn_s_barrier();
    asm volatile("s_waitcnt lgkmcnt(0)" ::: "memory");
    __builtin_amdgcn_sched_barrier(0);
    __builtin_amdgcn_s_setprio(1);
    #pragma unroll
    for (int mi=0; mi<4; mi++)
      #pragma unroll
      for (int ni=0; ni<4; ni++)
        acc[mi+4][ni] = __builtin_amdgcn_mfma_f32_16x16x32_bf16(af[mi], bfr[ni], acc[mi+4][ni], 0,0,0);
    __builtin_amdgcn_s_setprio(0);
    __builtin_amdgcn_s_barrier();

    #pragma unroll
    for (int ni=0; ni<4; ni++)
      bfr[ni] = *reinterpret_cast<const bf16x8*>(&Bsb[(((wc*64 + ni*16 + l15)*64) + 32 + g*8) ^ swz]);
    #pragma unroll
    for (int mi=0; mi<4; mi++)
      af[mi] = *reinterpret_cast<const bf16x8*>(&Asb[(((wr*128 + mi*16 + l15)*64) + 32 + g*8) ^ swz]);
    __builtin_amdgcn_s_barrier();
    asm volatile("s_waitcnt lgkmcnt(0)" ::: "memory");
    __builtin_amdgcn_sched_barrier(0);
    __builtin_amdgcn_s_setprio(1);
    #pragma unroll
    for (int mi=0; mi<4; mi++)
      #pragma unroll
      for (int ni=0; ni<4; ni++)
        acc[mi][ni] = __builtin_amdgcn_mfma_f32_16x16x32_bf16(af[mi], bfr[ni], acc[mi][ni], 0,0,0);
    __builtin_amdgcn_s_setprio(0);
    __builtin_amdgcn_s_barrier();

    #pragma unroll
    for (int mi=0; mi<4; mi++)
      af[mi] = *reinterpret_cast<const bf16x8*>(&Asb[(((wr*128 + (mi+4)*16 + l15)*64) + 32 + g*8) ^ swz]);
    __builtin_amdgcn_s_barrier();
    asm volatile("s_waitcnt lgkmcnt(0)" ::: "memory");
    __builtin_amdgcn_sched_barrier(0);
    __builtin_amdgcn_s_setprio(1);
    #pragma unroll
    for (int mi=0; mi<4; mi++)
      #pragma unroll
      for (int ni=0; ni<4; ni++)
        acc[mi+4][ni] = __builtin_amdgcn_mfma_f32_16x16x32_bf16(af[mi], bfr[ni], acc[mi+4][ni], 0,0,0);
    __builtin_amdgcn_s_setprio(0);
    asm volatile("s_waitcnt vmcnt(0)" ::: "memory");
    __builtin_amdgcn_s_barrier();
  }
#undef STG256

  #pragma unroll
  for (int mi=0; mi<8; mi++){
    #pragma unroll
    for (int ni=0; ni<4; ni++){
      const int cl = tn + wc*64 + ni*16 + l15;
      const int row0 = tm + wr*128 + mi*16 + g*4;
      if constexpr (OUTMODE == 0) {
        const float bb = bias[cl];
        #pragma unroll
        for (int r=0;r<4;r++)
          OutB[(size_t)(row0+r)*Dn + cl] = f2bf(acc[mi][ni][r] + bb);
      } else {
        #pragma unroll
        for (int r=0;r<4;r++)
          OutF[(size_t)(row0+r)*Dn + cl] = acc[mi][ni][r];
      }
    }
  }
}

// KV projection: R10-verified 128x128 ring kernel. Unchanged.
__global__ __launch_bounds__(256, 3) void kv_gemm(
  const unsigned short* __restrict__ Xb,
  const unsigned short* __restrict__ Wk,
  const unsigned short* __restrict__ Wv,
  const float* __restrict__ bk, const float* __restrict__ bv,
  unsigned short* __restrict__ Kp, unsigned short* __restrict__ Vt)
{
  __shared__ unsigned short As[3][128*32];
  __shared__ unsigned short Bs[3][128*32];
  const int tid = threadIdx.x;
  const int w = tid >> 6, l = tid & 63;
  const int l15 = l & 15, g = l >> 4;
  const int wr = w >> 1, wc = w & 1;
  const int nx = blockIdx.x + 28;
  const int tm = blockIdx.y * 128;

  const unsigned short* Wt; const float* bias; int colbase, mode;
  if (nx < 32) { Wt = Wk; bias = bk; colbase = (nx-28)*128; mode = 1; }
  else         { Wt = Wv; bias = bv; colbase = (nx-32)*128; mode = 2; }

  const f32x4 z = {0.f,0.f,0.f,0.f};
  f32x4 acc[4][4];
  #pragma unroll
  for (int i=0;i<4;i++)
    #pragma unroll
    for (int j=0;j<4;j++) acc[i][j] = z;

  const int lr  = l >> 2;
  const int lrs = lr ^ ((lr >> 2) & 1);
  const int lcs = ((l & 3) ^ (lrs & 3)) * 8;
  const unsigned short* Ab = Xb + (size_t)(tm + w*32 + lrs) * Dn + lcs;
  const unsigned short* Bb = Wt + (size_t)(colbase + w*32 + lrs) * Dn + lcs;

#define STAGE(KO, BUF) do {                                  \
    glds16(Ab + (KO),         &As[BUF][w*1024]);             \
    glds16(Ab + 16*Dn + (KO), &As[BUF][w*1024 + 512]);       \
    glds16(Bb + (KO),         &Bs[BUF][w*1024]);             \
    glds16(Bb + 16*Dn + (KO), &Bs[BUF][w*1024 + 512]);       \
  } while(0)

  const int nkt = Dn / 32;   // 112
  STAGE(0, 0);
  STAGE(32, 1);

  const int swz = (l15 & 7) << 3;

  for (int t = 0; t < nkt; ++t) {
    if (t + 1 < nkt) { asm volatile("s_waitcnt vmcnt(4)" ::: "memory"); }
    else             { asm volatile("s_waitcnt vmcnt(0)" ::: "memory"); }
    __builtin_amdgcn_s_barrier();
    __builtin_amdgcn_sched_barrier(0);
    const int nk = (t + 2) * 32;
    if (nk < Dn) STAGE(nk, (t + 2) % 3);

    const unsigned short* Asb = &As[t % 3][0];
    const unsigned short* Bsb = &Bs[t % 3][0];
    bf16x8 af[4], bfr[4];
    #pragma unroll
    for (int mi=0; mi<4; mi++)
      af[mi] = *reinterpret_cast<const bf16x8*>(&Asb[(((wr*64 + mi*16 + l15)*32 + g*8)) ^ swz]);
    #pragma unroll
    for (int ni=0; ni<4; ni++)
      bfr[ni] = *reinterpret_cast<const bf16x8*>(&Bsb[(((wc*64 + ni*16 + l15)*32 + g*8)) ^ swz]);
    __builtin_amdgcn_s_setprio(1);
    #pragma unroll
    for (int mi=0; mi<4; mi++)
      #pragma unroll
      for (int ni=0; ni<4; ni++)
        acc[mi][ni] = __builtin_amdgcn_mfma_f32_16x16x32_bf16(af[mi], bfr[ni], acc[mi][ni], 0,0,0);
    __builtin_amdgcn_s_setprio(0);
  }
#undef STAGE

  #pragma unroll
  for (int mi=0; mi<4; mi++){
    #pragma unroll
    for (int ni=0; ni<4; ni++){
      const int cl = wc*64 + ni*16 + l15;
      const float bb = bias[colbase + cl];
      if (mode == 2) {
        const int row0 = tm + wr*64 + mi*16 + g*4;
        const int b = row0 >> 11, sbase = row0 & 2047;
        ushort4 pk;
        pk.x = f2bf(acc[mi][ni][0] + bb);
        pk.y = f2bf(acc[mi][ni][1] + bb);
        pk.z = f2bf(acc[mi][ni][2] + bb);
        pk.w = f2bf(acc[mi][ni][3] + bb);
        *reinterpret_cast<ushort4*>(
          &Vt[(((size_t)b*KVn + (colbase>>7))*HDn + cl)*Sn + sbase]) = pk;
      } else {
        #pragma unroll
        for (int r=0;r<4;r++){
          const int row = tm + wr*64 + mi*16 + g*4 + r;
          Kp[(size_t)row*512 + colbase + cl] = f2bf(acc[mi][ni][r] + bb);
        }
      }
    }
  }
}

// RoPE + relayout, vectorized. K outputs pre-scaled by k2 = SCALING*log2e.
__global__ __launch_bounds__(256) void rope_kernel(
  const unsigned short* __restrict__ Qp, const unsigned short* __restrict__ Kp,
  const float* __restrict__ cosp, const float* __restrict__ sinp,
  unsigned short* __restrict__ Qh, unsigned short* __restrict__ Kh)
{
  const int t = threadIdx.x;
  const int bs = blockIdx.x;
  const int head = t >> 3;
  const int d0 = (t & 7) * 8;
  const int b = bs >> 11, s = bs & 2047;

  const float* cp = cosp + (size_t)bs*128;
  const float* sp = sinp + (size_t)bs*128;
  float4 cA0 = *reinterpret_cast<const float4*>(cp + d0);
  float4 cA1 = *reinterpret_cast<const float4*>(cp + d0 + 4);
  float4 cB0 = *reinterpret_cast<const float4*>(cp + d0 + 64);
  float4 cB1 = *reinterpret_cast<const float4*>(cp + d0 + 68);
  float4 sA0 = *reinterpret_cast<const float4*>(sp + d0);
  float4 sA1 = *reinterpret_cast<const float4*>(sp + d0 + 4);
  float4 sB0 = *reinterpret_cast<const float4*>(sp + d0 + 64);
  float4 sB1 = *reinterpret_cast<const float4*>(sp + d0 + 68);

  const unsigned short* src; unsigned short* dst; float kscale;
  if (head < Hn) {
    src = Qp + (size_t)bs*Dn + head*HDn;
    dst = Qh + (((size_t)b*Hn + head)*Sn + s)*HDn;
    kscale = 1.0f;
  } else {
    const int kvh = head - Hn;
    src = Kp + (size_t)bs*512 + kvh*HDn;
    dst = Kh + (((size_t)b*KVn + kvh)*Sn + s)*HDn;
    kscale = 0.08838834764831845f * 1.4426950408889634f;
  }

  union { int4 v; unsigned short u[8]; } lo, hi, olo, ohi;
  lo.v = *reinterpret_cast<const int4*>(src + d0);
  hi.v = *reinterpret_cast<const int4*>(src + d0 + 64);
  #pragma unroll
  for (int j=0;j<8;j++){
    const float ca = (j<4)? (&cA0.x)[j] : (&cA1.x)[j-4];
    const float cb = (j<4)? (&cB0.x)[j] : (&cB1.x)[j-4];
    const float sa = (j<4)? (&sA0.x)[j] : (&sA1.x)[j-4];
    const float sb = (j<4)? (&sB0.x)[j] : (&sB1.x)[j-4];
    const float x0 = bf2f(lo.u[j]), x1 = bf2f(hi.u[j]);
    olo.u[j] = f2bf((x0*ca - x1*sa) * kscale);
    ohi.u[j] = f2bf((x1*cb + x0*sb) * kscale);
  }
  *reinterpret_cast<int4*>(dst + d0)      = olo.v;
  *reinterpret_cast<int4*>(dst + d0 + 64) = ohi.v;
}

// Flash attention: R19 structure (best measured). Unchanged.
__global__ __launch_bounds__(256, 3) void attn_kernel(
  const unsigned short* __restrict__ Qh,
  const unsigned short* __restrict__ Kh,
  const unsigned short* __restrict__ Vt,
  unsigned short* __restrict__ ctx)
{
  __shared__ unsigned short Klds[64*136];
  __shared__ unsigned short Vlds[128*72];
  __shared__ __bf16 Plds[4][16*72];

  const int tid = threadIdx.x, w = tid>>6, l = tid&63;
  const int l15 = l&15, g = l>>4;
  const int bh = blockIdx.x;
  const int qt = (int)gridDim.y - 1 - (int)blockIdx.y;
  const int b = bh / Hn, h = bh % Hn;
  const int kv = h / 7;
  const int qbase = qt * 64;
  const size_t qoff = ((size_t)b*Hn + h) * Sn;
  const size_t koff = ((size_t)b*KVn + kv) * Sn;
  const unsigned short* Kg0 = Kh + koff*HDn;
  const unsigned short* Vg0 = Vt + ((size_t)b*KVn + kv)*HDn*Sn;

  bf16x8 qf[4];
  {
    const int qrow = qbase + w*16 + l15;
    #pragma unroll
    for (int st=0; st<4; st++)
      qf[st] = *reinterpret_cast<const bf16x8*>(Qh + (qoff + qrow)*HDn + st*32 + g*8);
  }

  const f32x4 z = {0.f,0.f,0.f,0.f};
  f32x4 o[8];
  #pragma unroll
  for (int dc=0; dc<8; dc++) o[dc] = z;
  f32x4 ls = z;
  float m_[4];
  #pragma unroll
  for (int r=0;r<4;r++) m_[r] = -1e30f;

  const bf16x8 onesv = {(__bf16)1.f,(__bf16)1.f,(__bf16)1.f,(__bf16)1.f,
                        (__bf16)1.f,(__bf16)1.f,(__bf16)1.f,(__bf16)1.f};

  const int k_r  = tid >> 4;
  const int k_c  = (tid & 15) * 8;
  const int v_d  = tid >> 3;
  const int v_s  = (tid & 7) * 8;

  const unsigned short* Kgp = Kg0 + (size_t)k_r*HDn + k_c;
  const unsigned short* Vgp = Vg0 + (size_t)v_d*Sn + v_s;

  int4 ka, kb, kc4, kd, va, vb, vc4, vd;

#define PREFETCH(KT) do {                                                     \
    const unsigned short* Kg_ = Kgp + (size_t)(KT)*64*HDn;                    \
    const unsigned short* Vg_ = Vgp + (size_t)(KT)*64;                        \
    ka  = *reinterpret_cast<const int4*>(Kg_);                                \
    kb  = *reinterpret_cast<const int4*>(Kg_ + 16*HDn);                       \
    kc4 = *reinterpret_cast<const int4*>(Kg_ + 32*HDn);                       \
    kd  = *reinterpret_cast<const int4*>(Kg_ + 48*HDn);                       \
    va  = *reinterpret_cast<const int4*>(Vg_);                                \
    vb  = *reinterpret_cast<const int4*>(Vg_ + (size_t)32*Sn);                \
    vc4 = *reinterpret_cast<const int4*>(Vg_ + (size_t)64*Sn);                \
    vd  = *reinterpret_cast<const int4*>(Vg_ + (size_t)96*Sn);                \
  } while(0)

  const int nkt = qt + 1;
  PREFETCH(0);

  for (int kt = 0; kt < nkt; kt++) {
    __syncthreads();
    *reinterpret_cast<int4*>(&Klds[(k_r     )*136 + k_c]) = ka;
    *reinterpret_cast<int4*>(&Klds[(k_r + 16)*136 + k_c]) = kb;
    *reinterpret_cast<int4*>(&Klds[(k_r + 32)*136 + k_c]) = kc4;
    *reinterpret_cast<int4*>(&Klds[(k_r + 48)*136 + k_c]) = kd;
    *reinterpret_cast<int4*>(&Vlds[(v_d     )*72 + v_s]) = va;
    *reinterpret_cast<int4*>(&Vlds[(v_d + 32)*72 + v_s]) = vb;
    *reinterpret_cast<int4*>(&Vlds[(v_d + 64)*72 + v_s]) = vc4;
    *reinterpret_cast<int4*>(&Vlds[(v_d + 96)*72 + v_s]) = vd;
    if (kt + 1 < nkt) PREFETCH(kt + 1);
    __syncthreads();

    // S = Q (k2*K)^T  — already in exp2 domain
    f32x4 sa[4];
    #pragma unroll
    for (int hc=0; hc<4; hc++) sa[hc] = z;
    __builtin_amdgcn_s_setprio(1);
    #pragma unroll
    for (int hc=0; hc<4; hc++){
      #pragma unroll
      for (int st=0; st<4; st++){
        const bf16x8 kf = *reinterpret_cast<const bf16x8*>(&Klds[(hc*16 + l15)*136 + st*32 + g*8]);
        sa[hc] = __builtin_amdgcn_mfma_f32_16x16x32_bf16(qf[st], kf, sa[hc], 0,0,0);
      }
    }
    __builtin_amdgcn_s_setprio(0);
    // causal mask: only the diagonal tile
    const int q0 = qbase + w*16 + g*4;
    if (kt == qt) {
      #pragma unroll
      for (int hc=0; hc<4; hc++){
        const int kc = kt*64 + hc*16 + l15;
        #pragma unroll
        for (int r=0;r<4;r++)
          sa[hc][r] = (kc <= q0 + r) ? sa[hc][r] : -1e30f;
      }
    }
    // online softmax: DPP max reduce; denominator on the matrix pipe
    f32x4 sfv;
    #pragma unroll
    for (int r=0;r<4;r++){
      float mx = fmaxf(fmaxf(sa[0][r], sa[1][r]), fmaxf(sa[2][r], sa[3][r]));
      mx = fmaxf(mx, dppf<0x128>(mx));
      mx = fmaxf(mx, dppf<0x124>(mx));
      mx = fmaxf(mx, dppf<0x122>(mx));
      mx = fmaxf(mx, dppf<0x121>(mx));
      const float mn = fmaxf(m_[r], mx);
      sfv[r] = exp2f(m_[r] - mn);
      m_[r] = mn;
    }
    #pragma unroll
    for (int hc=0; hc<4; hc++)
      #pragma unroll
      for (int r=0;r<4;r++)
        sa[hc][r] = exp2f(sa[hc][r] - m_[r]);
    #pragma unroll
    for (int dc=0; dc<8; dc++) o[dc] *= sfv;
    ls *= sfv;
    // P -> per-wave LDS -> A-fragments
    #pragma unroll
    for (int hc=0; hc<4; hc++)
      #pragma unroll
      for (int r=0;r<4;r++)
        Plds[w][(g*4+r)*72 + hc*16 + l15] = (__bf16)sa[hc][r];
    bf16x8 pf[2];
    pf[0] = *reinterpret_cast<const bf16x8*>(&Plds[w][l15*72 + g*8]);
    pf[1] = *reinterpret_cast<const bf16x8*>(&Plds[w][l15*72 + 32 + g*8]);
    // denominator + PV on the matrix pipe
    __builtin_amdgcn_s_setprio(1);
    ls = __builtin_amdgcn_mfma_f32_16x16x32_bf16(pf[0], onesv, ls, 0,0,0);
    ls = __builtin_amdgcn_mfma_f32_16x16x32_bf16(pf[1], onesv, ls, 0,0,0);
    #pragma unroll
    for (int dc=0; dc<8; dc++){
      #pragma unroll
      for (int ks=0; ks<2; ks++){
        const bf16x8 vf = *reinterpret_cast<const bf16x8*>(&Vlds[(dc*16 + l15)*72 + ks*32 + g*8]);
        o[dc] = __builtin_amdgcn_mfma_f32_16x16x32_bf16(pf[ks], vf, o[dc], 0,0,0);
      }
    }
    __builtin_amdgcn_s_setprio(0);
  }
#undef PREFETCH

  f32x4 linv;
  #pragma unroll
  for (int r=0;r<4;r++) linv[r] = 1.0f / ls[r];
  const int s0r = qbase + w*16 + g*4;
  #pragma unroll
  for (int dc=0; dc<8; dc++)
    #pragma unroll
    for (int r=0;r<4;r++)
      ctx[((size_t)b*Sn + s0r + r)*Dn + h*HDn + dc*16 + l15] = f2bf(o[dc][r] * linv[r]);
}

extern "C" void kernel_launch(void* const* d_in, const int* in_sizes, int n_in,
                              void* d_out, int out_size, void* d_ws, size_t ws_size,
                              hipStream_t stream)
{
  (void)in_sizes; (void)n_in; (void)out_size; (void)ws_size;
  const float* hidden = (const float*)d_in[0];
  const float* cosp   = (const float*)d_in[1];
  const float* sinp   = (const float*)d_in[2];
  // d_in[3] = attention_mask: pure causal by construction -> applied analytically
  const float* wq = (const float*)d_in[4];
  const float* bq = (const float*)d_in[5];
  const float* wk = (const float*)d_in[6];
  const float* bk = (const float*)d_in[7];
  const float* wv = (const float*)d_in[8];
  const float* bv = (const float*)d_in[9];
  const float* wo = (const float*)d_in[10];

  char* ws = (char*)d_ws;
  const size_t nX  = (size_t)Bn*Sn*Dn;       // 14,680,064
  const size_t nWq = (size_t)Hn*HDn*Dn;      // 12,845,056
  const size_t nWk = (size_t)KVn*HDn*Dn;     //  1,835,008
  const size_t nKV = (size_t)Bn*KVn*Sn*HDn;  //  2,097,152

  unsigned short* Xb  = (unsigned short*)(ws);                                   // -> reused as Qh
  unsigned short* Wqb = (unsigned short*)(ws + 2*nX);                            // -> reused as Wob
  unsigned short* Wkb = (unsigned short*)(ws + 2*(nX + nWq));
  unsigned short* Wvb = (unsigned short*)(ws + 2*(nX + nWq + nWk));
  unsigned short* Qp  = (unsigned short*)(ws + 2*(nX + nWq + 2*nWk));            // -> reused as ctx
  unsigned short* Kp  = (unsigned short*)(ws + 2*(2*nX + nWq + 2*nWk));
  unsigned short* Kh  = (unsigned short*)(ws + 2*(2*nX + nWq + 2*nWk + nKV));
  unsigned short* Vt  = (unsigned short*)(ws + 2*(2*nX + nWq + 2*nWk + 2*nKV));

  // fused pre-casts: X, Wq, Wk, Wv in one launch
  cast4_kernel<<<dim3(2048), dim3(256), 0, stream>>>(
      hidden, Xb,  (int)(nX/4),
      wq,     Wqb, (int)(nWq/4),
      wk,     Wkb, (int)(nWk/4),
      wv,     Wvb, (int)(nWk/4));

  gemm256<0><<<dim3(Dn/256, (Bn*Sn)/256), dim3(512), 0, stream>>>(Xb, Wqb, bq, Qp, nullptr);
  kv_gemm<<<dim3(8, 32), dim3(256), 0, stream>>>(Xb, Wkb, Wvb, bk, bv, Kp, Vt);

  {
    int n4 = (int)(nWq/4);
    cast_bf16_kernel<<<dim3(4096), dim3(256), 0, stream>>>(wo, Wqb, n4);  // Wob reuses Wqb
  }

  rope_kernel<<<dim3(Bn*Sn), dim3(256), 0, stream>>>(Qp, Kp, cosp, sinp, /*Qh=*/Xb, Kh);

  attn_kernel<<<dim3(Bn*Hn, Sn/64), dim3(256), 0, stream>>>(/*Qh=*/Xb, Kh, Vt, /*ctx=*/Qp);

  gemm256<1><<<dim3(Dn/256, (Bn*Sn)/256), dim3(512), 0, stream>>>(/*ctx=*/Qp, /*Wob=*/Wqb, nullptr, nullptr, (float*)d_out);
}